// Round 16
// baseline (370.088 us; speedup 1.0000x reference)
//
#include <hip/hip_runtime.h>
#include <hip/hip_bf16.h>

#define SS 2048
#define BB 16
#define DD 512

typedef __attribute__((ext_vector_type(4))) float f32x4;
typedef __attribute__((ext_vector_type(8))) short bf16x8;
typedef __attribute__((ext_vector_type(4))) unsigned short us4;
typedef unsigned short us;

#define MFMA16(a,b,c) __builtin_amdgcn_mfma_f32_16x16x32_bf16((a),(b),(c),0,0,0)
#define BAR() __builtin_amdgcn_s_barrier()
#define WAITV(n) asm volatile("s_waitcnt vmcnt(" #n ")" ::: "memory")
#define WAITL()  asm volatile("s_waitcnt lgkmcnt(0)" ::: "memory")

__device__ __forceinline__ unsigned short f2b(float f) {
    union { float f; unsigned u; } v; v.f = f;
    unsigned r = v.u + 0x7FFFu + ((v.u >> 16) & 1u);
    return (unsigned short)(r >> 16);
}

// 256B-row LDS tile, 4-bit XOR swizzle (16-slot spread)
__device__ __forceinline__ bf16x8 ldfrag8(const us* base, int row, int kelem) {
    int off = (row << 8) + (kelem << 1);
    off ^= (row & 15) << 4;
    return *(const bf16x8*)((const char*)base + off);
}
// 128B-row (k_gemm)
__device__ __forceinline__ bf16x8 ldfrag(const us* base, int row, int kelem, int rowshift) {
    int off = (row << rowshift) + (kelem << 1);
    off ^= (row & 7) << 4;
    return *(const bf16x8*)((const char*)base + off);
}

__device__ __forceinline__ void gl16(const void* g, void* l) {
    __builtin_amdgcn_global_load_lds(
        (const __attribute__((address_space(1))) unsigned*)g,
        (__attribute__((address_space(3))) unsigned*)l, 16, 0, 0);
}

// ---------------------------------------------------------------------------
// Prep: seq [S][B][D] fp32 -> Xb [B][S][D] bf16 and Xbt [B][D][S] bf16.
// ---------------------------------------------------------------------------
__global__ __launch_bounds__(256) void k_prep_x(const float* __restrict__ seq,
        us* __restrict__ Xb, us* __restrict__ Xbt) {
    __shared__ __align__(16) char L[64 * 128];
    const int tid = threadIdx.x;
    const int d0 = blockIdx.x * 64, s0 = blockIdx.y * 64, b = blockIdx.z;
    {
        int r = tid >> 2, seg = (tid & 3) * 16;
        const float* src = seq + (size_t)(s0 + r) * (BB * DD) + (size_t)b * DD + d0 + seg;
        __align__(16) us vals[16];
        #pragma unroll
        for (int q = 0; q < 4; ++q) {
            f32x4 v = *(const f32x4*)(src + q * 4);
            vals[q*4+0] = f2b(v.x); vals[q*4+1] = f2b(v.y);
            vals[q*4+2] = f2b(v.z); vals[q*4+3] = f2b(v.w);
        }
        us* xo = Xb + ((size_t)b * SS + s0 + r) * DD + d0 + seg;
        *(bf16x8*)xo       = *(bf16x8*)&vals[0];
        *(bf16x8*)(xo + 8) = *(bf16x8*)&vals[8];
        #pragma unroll
        for (int j = 0; j < 16; ++j) {
            int d = seg + j;
            int addr = (d * 128 + r * 2) ^ ((d & 7) << 4);
            *(us*)(L + addr) = vals[j];
        }
    }
    __syncthreads();
    {
        int d = tid >> 2, sseg = (tid & 3) * 16;
        int c = (d & 7) << 4;
        int base = d * 128 + sseg * 2;
        bf16x8 h0 = *(bf16x8*)(L + (base ^ c));
        bf16x8 h1 = *(bf16x8*)(L + ((base + 16) ^ c));
        us* o = Xbt + ((size_t)b * DD + d0 + d) * SS + s0 + sseg;
        *(bf16x8*)o       = h0;
        *(bf16x8*)(o + 8) = h1;
    }
}

// ---------------------------------------------------------------------------
// Gt[p][i] = (1/sqrt(D)) * sum_a Wv[a,i] * Wq[a,p]
// ---------------------------------------------------------------------------
__global__ __launch_bounds__(256) void k_prepG(const float* __restrict__ Wv,
        const float* __restrict__ Wq, us* __restrict__ Gt) {
    __shared__ float Sq[32][64], Sv[32][64];
    const int tid = threadIdx.x;
    const int p0 = blockIdx.x * 64, i0 = blockIdx.y * 64;
    const int tp = tid & 15, ti = tid >> 4;
    float acc[4][4] = {};
    for (int a0 = 0; a0 < DD; a0 += 32) {
        #pragma unroll
        for (int j = 0; j < 2; ++j) {
            int slot = tid + j * 256;
            int row = slot >> 4, c4 = (slot & 15) * 4;
            *(f32x4*)&Sq[row][c4] = *(const f32x4*)(Wq + (size_t)(a0 + row) * DD + p0 + c4);
            *(f32x4*)&Sv[row][c4] = *(const f32x4*)(Wv + (size_t)(a0 + row) * DD + i0 + c4);
        }
        __syncthreads();
        for (int a = 0; a < 32; ++a) {
            f32x4 q = *(f32x4*)&Sq[a][tp * 4];
            f32x4 v = *(f32x4*)&Sv[a][ti * 4];
            #pragma unroll
            for (int x = 0; x < 4; ++x)
                #pragma unroll
                for (int y = 0; y < 4; ++y)
                    acc[x][y] += q[x] * v[y];
        }
        __syncthreads();
    }
    const float sc = 0.044194173824159216f;
    #pragma unroll
    for (int x = 0; x < 4; ++x)
        #pragma unroll
        for (int y = 0; y < 4; ++y)
            Gt[(size_t)(p0 + tp * 4 + x) * DD + i0 + ti * 4 + y] = f2b(acc[x][y] * sc);
}

// u[p] = (1/sqrt(D)) * sum_a bv[a] * Wq[a,p]
__global__ __launch_bounds__(512) void k_prepU(const float* __restrict__ Wq,
        const float* __restrict__ bv, float* __restrict__ u) {
    int p = threadIdx.x;
    float s = 0.f;
    for (int a0 = 0; a0 < DD; a0 += 8) {
        #pragma unroll
        for (int j = 0; j < 8; ++j)
            s += bv[a0 + j] * Wq[(size_t)(a0 + j) * DD + p];
    }
    u[p] = s * 0.044194173824159216f;
}

__global__ void k_prepW(const float* __restrict__ Wk, us* __restrict__ Wkb) {
    int i = (blockIdx.x * 256 + threadIdx.x) * 4;
    f32x4 v = *(const f32x4*)(Wk + i);
    us4 o; o.x = f2b(v.x); o.y = f2b(v.y); o.z = f2b(v.z); o.w = f2b(v.w);
    *(us4*)(Wkb + i) = o;
}

// ---------------------------------------------------------------------------
// bf16 GEMM: C[row,n] = sum_k A[row,k]*Bm[n,k] + bias[n]
// ---------------------------------------------------------------------------
template<int OUTMODE>
__global__ __launch_bounds__(256, 2) void k_gemm(
        const us* __restrict__ A, const us* __restrict__ Bm,
        const float* __restrict__ bias, void* __restrict__ outp) {
    __shared__ __align__(16) us As[2][128 * 64];
    __shared__ __align__(16) us Bs[2][128 * 64];
    const int tid = threadIdx.x;
    const int lane = tid & 63;
    const int w = tid >> 6;
    const int wr = w >> 1, wc = w & 1;
    const int l15 = lane & 15, lg = lane >> 4;
    const int b = blockIdx.x >> 4;
    const int s0 = (blockIdx.x & 15) * 128;
    const int n0 = blockIdx.y * 128;
    const char* abase = (const char*)(A + ((size_t)b * SS + s0) * DD);
    const char* bbase = (const char*)Bm + (size_t)n0 * 1024;

    f32x4 acc[4][4];
    #pragma unroll
    for (int m = 0; m < 4; ++m)
        #pragma unroll
        for (int n = 0; n < 4; ++n) acc[m][n] = (f32x4)(0.0f);

    auto stage = [&](int db, int p) {
        #pragma unroll
        for (int j = 0; j < 4; ++j) {
            int x = (tid + j * 256) * 16;
            int gx = x ^ (((x >> 7) & 7) << 4);
            int row = gx >> 7, col = gx & 127;
            gl16(abase + (size_t)row * 1024 + p * 128 + col, (char*)As[db] + x);
            gl16(bbase + (size_t)row * 1024 + p * 128 + col, (char*)Bs[db] + x);
        }
    };

    stage(0, 0);
    for (int p = 0; p < 8; ++p) {
        if (p < 7) { stage((p + 1) & 1, p + 1); WAITV(8); }
        else       { WAITV(0); }
        BAR();
        const us* Ac = As[p & 1]; const us* Bc = Bs[p & 1];
        __builtin_amdgcn_s_setprio(1);
        #pragma unroll
        for (int kk = 0; kk < 2; ++kk) {
            bf16x8 af[4], bfr[4];
            #pragma unroll
            for (int m = 0; m < 4; ++m) af[m]  = ldfrag(Ac, 64 * wr + 16 * m + l15, kk * 32 + 8 * lg, 7);
            #pragma unroll
            for (int n = 0; n < 4; ++n) bfr[n] = ldfrag(Bc, 64 * wc + 16 * n + l15, kk * 32 + 8 * lg, 7);
            #pragma unroll
            for (int m = 0; m < 4; ++m)
                #pragma unroll
                for (int n = 0; n < 4; ++n)
                    acc[m][n] = MFMA16(af[m], bfr[n], acc[m][n]);
        }
        __builtin_amdgcn_s_setprio(0);
        BAR();
    }

    #pragma unroll
    for (int m = 0; m < 4; ++m) {
        #pragma unroll
        for (int n = 0; n < 4; ++n) {
            int col = n0 + 64 * wc + 16 * n + l15;
            float bia = bias[col];
            #pragma unroll
            for (int r = 0; r < 4; ++r) {
                int row = s0 + 64 * wr + 16 * m + 4 * lg + r;
                float v = acc[m][n][r] + bia;
                if (OUTMODE == 0)
                    ((us*)outp)[((size_t)b * SS + row) * DD + col] = f2b(v);
                else
                    ((float*)outp)[((size_t)row * BB + b) * DD + col] = v;
            }
        }
    }
}

// ---------------------------------------------------------------------------
// Flash attention v21 = r15 with PAIRED intervals on a 2x2 ring.
//   Ring-4 as 2 pairs: pair P0 = slots{0,1}, P1 = slots{2,3};
//   slot(c) = 2*((c>>1)&1) + (c&1).  Interval j reads pair (j&1) = chunks
//   {2j, 2j+1}; at interval START (right after BAR) it issues chunks
//   {2j+2, 2j+3} into the OTHER pair, which the barrier just proved free
//   (all waves' previous-interval reads are data-dep-retired before BAR).
//   One barrier per 64KB interval: rendezvous/step 9 -> 5, reads/registers/
//   layout/numerics byte-identical to the passing r15 kernel.  WAITV(0) at
//   interval start drains only the pair issued a full interval earlier.
//   sched_barrier(0) between the two 16-MFMA sub-phases pins transient
//   fragment pressure to r15's proven level (r9 spill lesson).
// ---------------------------------------------------------------------------
__global__ __launch_bounds__(512, 2) void k_attn(
        const us* __restrict__ Vtb, const us* __restrict__ Xb,
        const us* __restrict__ Xbt, us* __restrict__ Ob) {
    __shared__ __align__(16) us BUFS[4][16384];  // 2x2-pair ring, 128KB
    __shared__ __align__(16) us Pb[64 * 128];    // P [64 r][128 t], 256B rows, swz
    __shared__ float red[2][64];

    const int tid = threadIdx.x;
    const int lane = tid & 63;
    const int w = tid >> 6;
    const int rg = w & 3;          // rows 16*rg .. +15
    const int cg = w >> 2;         // t-half (QK) / e-half-within-quarter (PV)
    const int l15 = lane & 15, lg = lane >> 4;

    // XCD-batch locality (r11): XCD x = wg&7 -> batch 8*(wg>>8)+x
    const int wg = blockIdx.x;
    const int b  = ((wg >> 8) << 3) | (wg & 7);
    const int s0 = ((wg >> 3) & 31) * 64;

    const char* vbase  = (const char*)(Vtb + ((size_t)b * SS + s0) * DD);
    const char* xabase = (const char*)(Xb  + (size_t)b * SS * DD);
    const char* xtbase = (const char*)(Xbt + (size_t)b * DD * SS);

    // chunk c (8/step): i=c&7: i<4 -> X k-quarter i rows t0..t0+127;
    //                   i>=4 -> XT e-quarter (i-4) cols t0..t0+127
    auto issue = [&](int cflat, us* dst0) {
        int c = cflat & 127;
        int i = c & 7, t0 = (c >> 3) << 7;
        char* dst = (char*)dst0;
        if (i < 4) {
            #pragma unroll
            for (int j = 0; j < 4; ++j) {
                int x = tid * 16 + j * 8192;
                int gx = x ^ (((x >> 8) & 15) << 4);
                int row = gx >> 8, col = gx & 255;
                gl16(xabase + (size_t)(t0 + row) * 1024 + i * 256 + col, dst + x);
            }
        } else {
            #pragma unroll
            for (int j = 0; j < 4; ++j) {
                int x = tid * 16 + j * 8192;
                int gx = x ^ (((x >> 8) & 15) << 4);
                int row = gx >> 8, col = gx & 255;
                gl16(xtbase + (size_t)((i - 4) * 128 + row) * (SS * 2)
                            + (size_t)t0 * 2 + col, dst + x);
            }
        }
    };
    auto slotOf = [&](int c) { return 2 * ((c >> 1) & 1) + (c & 1); };

    // ---- prologue: Vt tile (64 rows x 512 k) -> af regs via 4x16KB subs ----
    #pragma unroll
    for (int p = 0; p < 4; ++p) {
        #pragma unroll
        for (int j = 0; j < 2; ++j) {
            int x = tid * 16 + j * 8192;
            int gx = x ^ (((x >> 8) & 15) << 4);
            int row = gx >> 8, col = gx & 255;
            gl16(vbase + (size_t)row * 1024 + p * 256 + col,
                 (char*)BUFS[0] + p * 16384 + x);
        }
    }
    WAITV(0); BAR();
    bf16x8 af[16];
    #pragma unroll
    for (int p = 0; p < 4; ++p)
        #pragma unroll
        for (int kk = 0; kk < 4; ++kk)
            af[4 * p + kk] = ldfrag8((const us*)BUFS[0] + p * 8192,
                                     16 * rg + l15, 32 * kk + 8 * lg);
    WAITL(); BAR();

    // bootstrap: issue pair for chunks {0,1}
    issue(0, BUFS[0]);
    issue(1, BUFS[1]);

    f32x4 accv[4][4];
    #pragma unroll
    for (int ph = 0; ph < 4; ++ph)
        #pragma unroll
        for (int nt = 0; nt < 4; ++nt) accv[ph][nt] = (f32x4)(0.0f);
    float lsum[4] = {0.f, 0.f, 0.f, 0.f};
    const int idx = 16 * rg + 4 * lg;

    for (int step = 0; step < 16; ++step) {
        const int cbase = step * 8;
        f32x4 sacc[4];
        #pragma unroll
        for (int nt = 0; nt < 4; ++nt) sacc[nt] = (f32x4)(0.0f);

        // -------- QK: 2 paired intervals (2 k-quarters each) --------
        #pragma unroll
        for (int jj = 0; jj < 2; ++jj) {
            const int c0 = cbase + 2 * jj;
            WAITV(0); BAR();
            issue(c0 + 2, BUFS[slotOf(c0 + 2)]);
            issue(c0 + 3, BUFS[slotOf(c0 + 3)]);
            __builtin_amdgcn_s_setprio(1);
            #pragma unroll
            for (int half = 0; half < 2; ++half) {
                const int c = c0 + half;
                const int kq = 2 * jj + half;
                const us* sl = BUFS[slotOf(c)];
                #pragma unroll
                for (int kk = 0; kk < 4; ++kk)
                    #pragma unroll
                    for (int nt = 0; nt < 4; ++nt) {
                        bf16x8 bq = ldfrag8(sl, 64 * cg + 16 * nt + l15, 32 * kk + 8 * lg);
                        sacc[nt] = MFMA16(af[4 * kq + kk], bq, sacc[nt]);
                    }
                __builtin_amdgcn_sched_barrier(0);
            }
            __builtin_amdgcn_s_setprio(0);
        }

        // -------- softmax (static max): P = exp(s) --------
        #pragma unroll
        for (int nt = 0; nt < 4; ++nt)
            #pragma unroll
            for (int ri = 0; ri < 4; ++ri)
                sacc[nt][ri] = __expf(sacc[nt][ri]);
        #pragma unroll
        for (int nt = 0; nt < 4; ++nt)
            #pragma unroll
            for (int ri = 0; ri < 4; ++ri) {
                int row = idx + ri;
                int col = 64 * cg + 16 * nt + l15;
                int off = ((row << 8) + (col << 1)) ^ ((row & 15) << 4);
                *(us*)((char*)Pb + off) = f2b(sacc[nt][ri]);
            }
        #pragma unroll
        for (int ri = 0; ri < 4; ++ri) {
            float s = sacc[0][ri] + sacc[1][ri] + sacc[2][ri] + sacc[3][ri];
            s += __shfl_xor(s, 1); s += __shfl_xor(s, 2);
            s += __shfl_xor(s, 4); s += __shfl_xor(s, 8);
            lsum[ri] += s;
        }
        WAITL(); BAR();
        bf16x8 pa[4];
        #pragma unroll
        for (int kk = 0; kk < 4; ++kk)
            pa[kk] = ldfrag8(Pb, 16 * rg + l15, 32 * kk + 8 * lg);

        // -------- PV: 2 paired intervals (2 e-quarters each) --------
        #pragma unroll
        for (int jj = 0; jj < 2; ++jj) {
            const int c0 = cbase + 4 + 2 * jj;
            WAITV(0); BAR();
            issue(c0 + 2, BUFS[slotOf(c0 + 2)]);
            issue(c0 + 3, BUFS[slotOf(c0 + 3)]);
            __builtin_amdgcn_s_setprio(1);
            #pragma unroll
            for (int half = 0; half < 2; ++half) {
                const int c = c0 + half;
                const int ep = 2 * jj + half;
                const us* sl = BUFS[slotOf(c)];
                #pragma unroll
                for (int kk = 0; kk < 4; ++kk)
                    #pragma unroll
                    for (int nt = 0; nt < 4; ++nt) {
                        bf16x8 bx = ldfrag8(sl, 64 * cg + 16 * nt + l15, 32 * kk + 8 * lg);
                        accv[ep][nt] = MFMA16(pa[kk], bx, accv[ep][nt]);
                    }
                __builtin_amdgcn_sched_barrier(0);
            }
            __builtin_amdgcn_s_setprio(0);
        }
    }

    WAITV(0);
    // -------- epilogue: cross-cg sum, O' = acc / tot --------
    if (l15 == 0) {
        #pragma unroll
        for (int ri = 0; ri < 4; ++ri)
            red[cg][idx + ri] = lsum[ri];
    }
    WAITL(); BAR();
    float tot[4];
    #pragma unroll
    for (int ri = 0; ri < 4; ++ri)
        tot[ri] = red[0][idx + ri] + red[1][idx + ri];
    us* orow = Ob + ((size_t)b * SS + s0) * DD;
    #pragma unroll
    for (int ph = 0; ph < 4; ++ph)
        #pragma unroll
        for (int nt = 0; nt < 4; ++nt)
            #pragma unroll
            for (int ri = 0; ri < 4; ++ri) {
                int row = idx + ri;
                int e = 128 * ph + 64 * cg + 16 * nt + l15;
                orow[(size_t)row * DD + e] = f2b(accv[ph][nt][ri] / tot[ri]);
            }
}

extern "C" void kernel_launch(void* const* d_in, const int* in_sizes, int n_in,
                              void* d_out, int out_size, void* d_ws, size_t ws_size,
                              hipStream_t stream) {
    const float* seq = (const float*)d_in[0];
    const float* Wv  = (const float*)d_in[1];
    const float* bv  = (const float*)d_in[2];
    const float* Wq  = (const float*)d_in[3];
    // d_in[4] = bq: softmax-row-constant -> unused
    const float* Wk  = (const float*)d_in[5];
    const float* bk  = (const float*)d_in[6];

    char* ws = (char*)d_ws;
    us*    Xb  = (us*)ws;                                  // [B][S][D] bf16, 32MB
    us*    Xbt = (us*)(ws + (size_t)33554432);             // [B][D][S] bf16, 32MB
    us*    Vtb = (us*)(ws + (size_t)67108864);             // [B][S][D] bf16, 32MB (reused as O')
    us*    Gt  = (us*)(ws + (size_t)100663296);            // [D][D] bf16
    us*    Wkb = (us*)(ws + (size_t)101187584);            // [D][D] bf16
    float* u   = (float*)(ws + (size_t)101711872);         // [D] fp32

    k_prep_x<<<dim3(8, 32, 16), 256, 0, stream>>>(seq, Xb, Xbt);
    k_prepG<<<dim3(8, 8), 256, 0, stream>>>(Wv, Wq, Gt);
    k_prepU<<<1, 512, 0, stream>>>(Wq, bv, u);
    k_prepW<<<256, 256, 0, stream>>>(Wk, Wkb);

    k_gemm<0><<<dim3(256, 4), 256, 0, stream>>>(Xb, Gt, u, (void*)Vtb);   // Vt = X*G + u
    k_attn<<<512, 512, 0, stream>>>(Vtb, Xb, Xbt, Vtb);                   // O' over Vt
    k_gemm<1><<<dim3(256, 4), 256, 0, stream>>>(Vtb, Wkb, bk, d_out);     // out = O'*Wk^T + bk
}

// Round 17
// 343.916 us; speedup vs baseline: 1.0761x; 1.0761x over previous
//
#include <hip/hip_runtime.h>
#include <hip/hip_bf16.h>

#define SS 2048
#define BB 16
#define DD 512

typedef __attribute__((ext_vector_type(4))) float f32x4;
typedef __attribute__((ext_vector_type(8))) short bf16x8;
typedef __attribute__((ext_vector_type(4))) unsigned short us4;
typedef unsigned short us;

#define MFMA16(a,b,c) __builtin_amdgcn_mfma_f32_16x16x32_bf16((a),(b),(c),0,0,0)
#define BAR() __builtin_amdgcn_s_barrier()
#define WAITV(n) asm volatile("s_waitcnt vmcnt(" #n ")" ::: "memory")
#define WAITL()  asm volatile("s_waitcnt lgkmcnt(0)" ::: "memory")

__device__ __forceinline__ unsigned short f2b(float f) {
    union { float f; unsigned u; } v; v.f = f;
    unsigned r = v.u + 0x7FFFu + ((v.u >> 16) & 1u);
    return (unsigned short)(r >> 16);
}

// 256B-row LDS tile, 4-bit XOR swizzle (16-slot spread)
__device__ __forceinline__ bf16x8 ldfrag8(const us* base, int row, int kelem) {
    int off = (row << 8) + (kelem << 1);
    off ^= (row & 15) << 4;
    return *(const bf16x8*)((const char*)base + off);
}
// 128B-row (gemm tiles)
__device__ __forceinline__ bf16x8 ldfrag(const us* base, int row, int kelem, int rowshift) {
    int off = (row << rowshift) + (kelem << 1);
    off ^= (row & 7) << 4;
    return *(const bf16x8*)((const char*)base + off);
}

__device__ __forceinline__ void gl16(const void* g, void* l) {
    __builtin_amdgcn_global_load_lds(
        (const __attribute__((address_space(1))) unsigned*)g,
        (__attribute__((address_space(3))) unsigned*)l, 16, 0, 0);
}

// ---------------------------------------------------------------------------
// Prep: seq [S][B][D] fp32 -> Xb [B][S][D] bf16 and Xbt [B][D][S] bf16.
// ---------------------------------------------------------------------------
__global__ __launch_bounds__(256) void k_prep_x(const float* __restrict__ seq,
        us* __restrict__ Xb, us* __restrict__ Xbt) {
    __shared__ __align__(16) char L[64 * 128];
    const int tid = threadIdx.x;
    const int d0 = blockIdx.x * 64, s0 = blockIdx.y * 64, b = blockIdx.z;
    {
        int r = tid >> 2, seg = (tid & 3) * 16;
        const float* src = seq + (size_t)(s0 + r) * (BB * DD) + (size_t)b * DD + d0 + seg;
        __align__(16) us vals[16];
        #pragma unroll
        for (int q = 0; q < 4; ++q) {
            f32x4 v = *(const f32x4*)(src + q * 4);
            vals[q*4+0] = f2b(v.x); vals[q*4+1] = f2b(v.y);
            vals[q*4+2] = f2b(v.z); vals[q*4+3] = f2b(v.w);
        }
        us* xo = Xb + ((size_t)b * SS + s0 + r) * DD + d0 + seg;
        *(bf16x8*)xo       = *(bf16x8*)&vals[0];
        *(bf16x8*)(xo + 8) = *(bf16x8*)&vals[8];
        #pragma unroll
        for (int j = 0; j < 16; ++j) {
            int d = seg + j;
            int addr = (d * 128 + r * 2) ^ ((d & 7) << 4);
            *(us*)(L + addr) = vals[j];
        }
    }
    __syncthreads();
    {
        int d = tid >> 2, sseg = (tid & 3) * 16;
        int c = (d & 7) << 4;
        int base = d * 128 + sseg * 2;
        bf16x8 h0 = *(bf16x8*)(L + (base ^ c));
        bf16x8 h1 = *(bf16x8*)(L + ((base + 16) ^ c));
        us* o = Xbt + ((size_t)b * DD + d0 + d) * SS + s0 + sseg;
        *(bf16x8*)o       = h0;
        *(bf16x8*)(o + 8) = h1;
    }
}

// ---------------------------------------------------------------------------
// Gt[p][i] = (1/sqrt(D)) * sum_a Wv[a,i] * Wq[a,p]
// ---------------------------------------------------------------------------
__global__ __launch_bounds__(256) void k_prepG(const float* __restrict__ Wv,
        const float* __restrict__ Wq, us* __restrict__ Gt) {
    __shared__ float Sq[32][64], Sv[32][64];
    const int tid = threadIdx.x;
    const int p0 = blockIdx.x * 64, i0 = blockIdx.y * 64;
    const int tp = tid & 15, ti = tid >> 4;
    float acc[4][4] = {};
    for (int a0 = 0; a0 < DD; a0 += 32) {
        #pragma unroll
        for (int j = 0; j < 2; ++j) {
            int slot = tid + j * 256;
            int row = slot >> 4, c4 = (slot & 15) * 4;
            *(f32x4*)&Sq[row][c4] = *(const f32x4*)(Wq + (size_t)(a0 + row) * DD + p0 + c4);
            *(f32x4*)&Sv[row][c4] = *(const f32x4*)(Wv + (size_t)(a0 + row) * DD + i0 + c4);
        }
        __syncthreads();
        for (int a = 0; a < 32; ++a) {
            f32x4 q = *(f32x4*)&Sq[a][tp * 4];
            f32x4 v = *(f32x4*)&Sv[a][ti * 4];
            #pragma unroll
            for (int x = 0; x < 4; ++x)
                #pragma unroll
                for (int y = 0; y < 4; ++y)
                    acc[x][y] += q[x] * v[y];
        }
        __syncthreads();
    }
    const float sc = 0.044194173824159216f;
    #pragma unroll
    for (int x = 0; x < 4; ++x)
        #pragma unroll
        for (int y = 0; y < 4; ++y)
            Gt[(size_t)(p0 + tp * 4 + x) * DD + i0 + ti * 4 + y] = f2b(acc[x][y] * sc);
}

// u[p] = (1/sqrt(D)) * sum_a bv[a] * Wq[a,p]
__global__ __launch_bounds__(512) void k_prepU(const float* __restrict__ Wq,
        const float* __restrict__ bv, float* __restrict__ u) {
    int p = threadIdx.x;
    float s = 0.f;
    for (int a0 = 0; a0 < DD; a0 += 8) {
        #pragma unroll
        for (int j = 0; j < 8; ++j)
            s += bv[a0 + j] * Wq[(size_t)(a0 + j) * DD + p];
    }
    u[p] = s * 0.044194173824159216f;
}

__global__ void k_prepW(const float* __restrict__ Wk, us* __restrict__ Wkb) {
    int i = (blockIdx.x * 256 + threadIdx.x) * 4;
    f32x4 v = *(const f32x4*)(Wk + i);
    us4 o; o.x = f2b(v.x); o.y = f2b(v.y); o.z = f2b(v.z); o.w = f2b(v.w);
    *(us4*)(Wkb + i) = o;
}

// ---------------------------------------------------------------------------
// Generalized batched bf16 GEMM, 128x128 tile, BK=64, dbuf+counted vmcnt.
//   C[row,n] = sum_k A[za][s0+row][k] * B[zb][n0+n][k]
//   MODE 0: P = exp(acc) -> bf16 out [oStr][ldc]; row-sums atomicAdd to Ls.
//   MODE 1: bf16 out (no bias).
//   MODE 2: fp32 out at [(row*BB+zo)*DD+col] = acc/Ls[row] + bias[col].
//   MODE 3: bf16 out + bias.
// ---------------------------------------------------------------------------
template<int MODE>
__global__ __launch_bounds__(256, 2) void k_bgemm(
        const us* __restrict__ A, const us* __restrict__ Bm,
        const float* __restrict__ bias, float* __restrict__ Ls,
        void* __restrict__ outp,
        int K, int lda, int ldb, int ldc,
        long aStr, long bStr, long oStr,
        int aB, int bB, int oB, int lsB) {
    __shared__ __align__(16) us As[2][128 * 64];
    __shared__ __align__(16) us Bs[2][128 * 64];
    const int tid = threadIdx.x;
    const int lane = tid & 63;
    const int w = tid >> 6;
    const int wr = w >> 1, wc = w & 1;
    const int l15 = lane & 15, lg = lane >> 4;
    const int s0 = blockIdx.x * 128;
    const int n0 = blockIdx.y * 128;
    const int za = aB + blockIdx.z, zb = bB + blockIdx.z;
    const int zo = oB + blockIdx.z, zl = lsB + blockIdx.z;
    const char* abase = (const char*)(A + (size_t)za * aStr + (size_t)s0 * lda);
    const char* bbase = (const char*)(Bm + (size_t)zb * bStr + (size_t)n0 * ldb);
    const size_t arow = (size_t)lda * 2, brow = (size_t)ldb * 2;

    f32x4 acc[4][4];
    #pragma unroll
    for (int m = 0; m < 4; ++m)
        #pragma unroll
        for (int n = 0; n < 4; ++n) acc[m][n] = (f32x4)(0.0f);

    auto stage = [&](int db, int p) {
        #pragma unroll
        for (int j = 0; j < 4; ++j) {
            int x = (tid + j * 256) * 16;
            int gx = x ^ (((x >> 7) & 7) << 4);
            int row = gx >> 7, col = gx & 127;
            gl16(abase + (size_t)row * arow + p * 128 + col, (char*)As[db] + x);
            gl16(bbase + (size_t)row * brow + p * 128 + col, (char*)Bs[db] + x);
        }
    };

    const int nPh = K >> 6;
    stage(0, 0);
    for (int p = 0; p < nPh; ++p) {
        if (p < nPh - 1) { stage((p + 1) & 1, p + 1); WAITV(8); }
        else             { WAITV(0); }
        BAR();
        const us* Ac = As[p & 1]; const us* Bc = Bs[p & 1];
        __builtin_amdgcn_s_setprio(1);
        #pragma unroll
        for (int kk = 0; kk < 2; ++kk) {
            bf16x8 af[4], bfr[4];
            #pragma unroll
            for (int m = 0; m < 4; ++m) af[m]  = ldfrag(Ac, 64 * wr + 16 * m + l15, kk * 32 + 8 * lg, 7);
            #pragma unroll
            for (int n = 0; n < 4; ++n) bfr[n] = ldfrag(Bc, 64 * wc + 16 * n + l15, kk * 32 + 8 * lg, 7);
            #pragma unroll
            for (int m = 0; m < 4; ++m)
                #pragma unroll
                for (int n = 0; n < 4; ++n)
                    acc[m][n] = MFMA16(af[m], bfr[n], acc[m][n]);
        }
        __builtin_amdgcn_s_setprio(0);
        BAR();
    }

    if (MODE == 0) {
        us* o = (us*)outp + (size_t)zo * oStr;
        float rs[4][4];
        #pragma unroll
        for (int m = 0; m < 4; ++m)
            #pragma unroll
            for (int r = 0; r < 4; ++r) rs[m][r] = 0.0f;
        #pragma unroll
        for (int m = 0; m < 4; ++m)
            #pragma unroll
            for (int n = 0; n < 4; ++n) {
                int col = n0 + 64 * wc + 16 * n + l15;
                #pragma unroll
                for (int r = 0; r < 4; ++r) {
                    int row = s0 + 64 * wr + 16 * m + 4 * lg + r;
                    float pe = __expf(acc[m][n][r]);
                    rs[m][r] += pe;
                    o[(size_t)row * ldc + col] = f2b(pe);
                }
            }
        #pragma unroll
        for (int m = 0; m < 4; ++m)
            #pragma unroll
            for (int r = 0; r < 4; ++r) {
                float v = rs[m][r];
                v += __shfl_xor(v, 1); v += __shfl_xor(v, 2);
                v += __shfl_xor(v, 4); v += __shfl_xor(v, 8);
                if (l15 == 0)
                    atomicAdd(&Ls[(size_t)zl * SS + s0 + 64 * wr + 16 * m + 4 * lg + r], v);
            }
    } else if (MODE == 2) {
        float* o = (float*)outp;
        #pragma unroll
        for (int m = 0; m < 4; ++m)
            #pragma unroll
            for (int n = 0; n < 4; ++n) {
                int col = n0 + 64 * wc + 16 * n + l15;
                float bia = bias[col];
                #pragma unroll
                for (int r = 0; r < 4; ++r) {
                    int row = s0 + 64 * wr + 16 * m + 4 * lg + r;
                    float L = Ls[(size_t)zl * SS + row];
                    o[((size_t)row * BB + zo) * DD + col] = acc[m][n][r] / L + bia;
                }
            }
    } else {
        us* o = (us*)outp + (size_t)zo * oStr;
        #pragma unroll
        for (int m = 0; m < 4; ++m)
            #pragma unroll
            for (int n = 0; n < 4; ++n) {
                int col = n0 + 64 * wc + 16 * n + l15;
                float bia = (MODE == 3) ? bias[col] : 0.0f;
                #pragma unroll
                for (int r = 0; r < 4; ++r) {
                    int row = s0 + 64 * wr + 16 * m + 4 * lg + r;
                    o[(size_t)row * ldc + col] = f2b(acc[m][n][r] + bia);
                }
            }
    }
}

// ---------------------------------------------------------------------------
// FALLBACK flash attention (r15 v19, 249us) — used only if ws too small.
// ---------------------------------------------------------------------------
__global__ __launch_bounds__(512, 2) void k_attn(
        const us* __restrict__ Vtb, const us* __restrict__ Xb,
        const us* __restrict__ Xbt, us* __restrict__ Ob) {
    __shared__ __align__(16) us BUFS[4][16384];
    __shared__ __align__(16) us Pb[64 * 128];
    __shared__ float red[2][64];

    const int tid = threadIdx.x;
    const int lane = tid & 63;
    const int w = tid >> 6;
    const int rg = w & 3;
    const int cg = w >> 2;
    const int l15 = lane & 15, lg = lane >> 4;

    const int wg = blockIdx.x;
    const int b  = ((wg >> 8) << 3) | (wg & 7);
    const int s0 = ((wg >> 3) & 31) * 64;

    const char* vbase  = (const char*)(Vtb + ((size_t)b * SS + s0) * DD);
    const char* xabase = (const char*)(Xb  + (size_t)b * SS * DD);
    const char* xtbase = (const char*)(Xbt + (size_t)b * DD * SS);

    auto issue = [&](int cflat, us* dst0) {
        int c = cflat & 127;
        int i = c & 7, t0 = (c >> 3) << 7;
        char* dst = (char*)dst0;
        if (i < 4) {
            #pragma unroll
            for (int j = 0; j < 4; ++j) {
                int x = tid * 16 + j * 8192;
                int gx = x ^ (((x >> 8) & 15) << 4);
                int row = gx >> 8, col = gx & 255;
                gl16(xabase + (size_t)(t0 + row) * 1024 + i * 256 + col, dst + x);
            }
        } else {
            #pragma unroll
            for (int j = 0; j < 4; ++j) {
                int x = tid * 16 + j * 8192;
                int gx = x ^ (((x >> 8) & 15) << 4);
                int row = gx >> 8, col = gx & 255;
                gl16(xtbase + (size_t)((i - 4) * 128 + row) * (SS * 2)
                            + (size_t)t0 * 2 + col, dst + x);
            }
        }
    };

    #pragma unroll
    for (int p = 0; p < 4; ++p) {
        #pragma unroll
        for (int j = 0; j < 2; ++j) {
            int x = tid * 16 + j * 8192;
            int gx = x ^ (((x >> 8) & 15) << 4);
            int row = gx >> 8, col = gx & 255;
            gl16(vbase + (size_t)row * 1024 + p * 256 + col,
                 (char*)BUFS[0] + p * 16384 + x);
        }
    }
    WAITV(0); BAR();
    bf16x8 af[16];
    #pragma unroll
    for (int p = 0; p < 4; ++p)
        #pragma unroll
        for (int kk = 0; kk < 4; ++kk)
            af[4 * p + kk] = ldfrag8((const us*)BUFS[0] + p * 8192,
                                     16 * rg + l15, 32 * kk + 8 * lg);
    WAITL(); BAR();

    issue(0, BUFS[0]);
    issue(1, BUFS[1]);
    issue(2, BUFS[2]);

    f32x4 accv[4][4];
    #pragma unroll
    for (int ph = 0; ph < 4; ++ph)
        #pragma unroll
        for (int nt = 0; nt < 4; ++nt) accv[ph][nt] = (f32x4)(0.0f);
    float lsum[4] = {0.f, 0.f, 0.f, 0.f};
    const int idx = 16 * rg + 4 * lg;

    for (int step = 0; step < 16; ++step) {
        const int cbase = step * 8;
        f32x4 sacc[4];
        #pragma unroll
        for (int nt = 0; nt < 4; ++nt) sacc[nt] = (f32x4)(0.0f);

        #pragma unroll
        for (int p = 0; p < 4; ++p) {
            const int c = cbase + p;
            WAITV(8); BAR();
            const us* sl = BUFS[c & 3];
            __builtin_amdgcn_s_setprio(1);
            #pragma unroll
            for (int kk = 0; kk < 4; ++kk)
                #pragma unroll
                for (int nt = 0; nt < 4; ++nt) {
                    bf16x8 bq = ldfrag8(sl, 64 * cg + 16 * nt + l15, 32 * kk + 8 * lg);
                    sacc[nt] = MFMA16(af[4 * p + kk], bq, sacc[nt]);
                }
            __builtin_amdgcn_s_setprio(0);
            issue(c + 3, BUFS[(c + 3) & 3]);
        }

        #pragma unroll
        for (int nt = 0; nt < 4; ++nt)
            #pragma unroll
            for (int ri = 0; ri < 4; ++ri)
                sacc[nt][ri] = __expf(sacc[nt][ri]);
        #pragma unroll
        for (int nt = 0; nt < 4; ++nt)
            #pragma unroll
            for (int ri = 0; ri < 4; ++ri) {
                int row = idx + ri;
                int col = 64 * cg + 16 * nt + l15;
                int off = ((row << 8) + (col << 1)) ^ ((row & 15) << 4);
                *(us*)((char*)Pb + off) = f2b(sacc[nt][ri]);
            }
        #pragma unroll
        for (int ri = 0; ri < 4; ++ri) {
            float s = sacc[0][ri] + sacc[1][ri] + sacc[2][ri] + sacc[3][ri];
            s += __shfl_xor(s, 1); s += __shfl_xor(s, 2);
            s += __shfl_xor(s, 4); s += __shfl_xor(s, 8);
            lsum[ri] += s;
        }
        WAITL(); BAR();
        bf16x8 pa[4];
        #pragma unroll
        for (int kk = 0; kk < 4; ++kk)
            pa[kk] = ldfrag8(Pb, 16 * rg + l15, 32 * kk + 8 * lg);

        #pragma unroll
        for (int p = 0; p < 4; ++p) {
            const int c = cbase + 4 + p;
            WAITV(8); BAR();
            const us* sl = BUFS[c & 3];
            __builtin_amdgcn_s_setprio(1);
            #pragma unroll
            for (int kk = 0; kk < 4; ++kk)
                #pragma unroll
                for (int nt = 0; nt < 4; ++nt) {
                    bf16x8 bx = ldfrag8(sl, 64 * cg + 16 * nt + l15, 32 * kk + 8 * lg);
                    accv[p][nt] = MFMA16(pa[kk], bx, accv[p][nt]);
                }
            __builtin_amdgcn_s_setprio(0);
            issue(c + 3, BUFS[(c + 3) & 3]);
        }
    }

    WAITV(0);
    if (l15 == 0) {
        #pragma unroll
        for (int ri = 0; ri < 4; ++ri)
            red[cg][idx + ri] = lsum[ri];
    }
    WAITL(); BAR();
    float tot[4];
    #pragma unroll
    for (int ri = 0; ri < 4; ++ri)
        tot[ri] = red[0][idx + ri] + red[1][idx + ri];
    us* orow = Ob + ((size_t)b * SS + s0) * DD;
    #pragma unroll
    for (int ph = 0; ph < 4; ++ph)
        #pragma unroll
        for (int nt = 0; nt < 4; ++nt)
            #pragma unroll
            for (int ri = 0; ri < 4; ++ri) {
                int row = idx + ri;
                int e = 128 * ph + 64 * cg + 16 * nt + l15;
                orow[(size_t)row * DD + e] = f2b(accv[ph][nt][ri] / tot[ri]);
            }
}

extern "C" void kernel_launch(void* const* d_in, const int* in_sizes, int n_in,
                              void* d_out, int out_size, void* d_ws, size_t ws_size,
                              hipStream_t stream) {
    const float* seq = (const float*)d_in[0];
    const float* Wv  = (const float*)d_in[1];
    const float* bv  = (const float*)d_in[2];
    const float* Wq  = (const float*)d_in[3];
    // d_in[4] = bq: softmax-row-constant -> unused
    const float* Wk  = (const float*)d_in[5];
    const float* bk  = (const float*)d_in[6];

    char* ws = (char*)d_ws;
    us*    Xb  = (us*)ws;                                  // [B][S][D] bf16, 32MB
    us*    Xbt = (us*)(ws + (size_t)33554432);             // [B][D][S] bf16, 32MB
    us*    Vtb = (us*)(ws + (size_t)67108864);             // [B][S][D] bf16, 32MB
    us*    Gt  = (us*)(ws + (size_t)100663296);            // [D][D] bf16
    us*    Wkb = (us*)(ws + (size_t)101187584);            // [D][D] bf16
    float* u   = (float*)(ws + (size_t)101711872);         // [D] fp32
    float* Ls  = (float*)(ws + (size_t)101713920);         // [B][S] fp32, 128KB
    const size_t POFF = 101844992ull;
    us*    P   = (us*)(ws + POFF);                         // [gb][S][S] bf16

    long gb = 0;
    if (ws_size > POFF) {
        size_t cap = ws_size - POFF;
        for (long g = 16; g >= 1; g >>= 1)
            if ((size_t)g * SS * SS * 2 <= cap) { gb = g; break; }
    }

    k_prep_x<<<dim3(8, 32, 16), 256, 0, stream>>>(seq, Xb, Xbt);
    k_prepG<<<dim3(8, 8), 256, 0, stream>>>(Wv, Wq, Gt);
    k_prepU<<<1, 512, 0, stream>>>(Wq, bv, u);
    k_prepW<<<256, 256, 0, stream>>>(Wk, Wkb);

    // Vt = X*G + u  (bf16 out, bias)
    k_bgemm<3><<<dim3(16, 4, 16), 256, 0, stream>>>(
        Xb, Gt, u, nullptr, (void*)Vtb,
        512, 512, 512, 512, (long)SS * DD, 0, (long)SS * DD, 0, 0, 0, 0);

    if (gb >= 1) {
        hipMemsetAsync(Ls, 0, (size_t)BB * SS * 4, stream);
        for (int g = 0; g < 16; g += (int)gb) {
            // P = exp(Vt * X^T), row-sums -> Ls
            k_bgemm<0><<<dim3(16, 16, (int)gb), 256, 0, stream>>>(
                Vtb, Xb, nullptr, Ls, (void*)P,
                512, 512, 512, 2048, (long)SS * DD, (long)SS * DD, (long)SS * SS,
                g, g, 0, g);
            // O' = P * X  (via Xbt as B), overwrite Vtb
            k_bgemm<1><<<dim3(16, 4, (int)gb), 256, 0, stream>>>(
                P, Xbt, nullptr, nullptr, (void*)Vtb,
                2048, 2048, 2048, 512, (long)SS * SS, (long)DD * SS, (long)SS * DD,
                0, g, g, 0);
        }
        // out = O' * Wk^T / L + bk   (fp32, [S][B][D])
        k_bgemm<2><<<dim3(16, 4, 16), 256, 0, stream>>>(
            Vtb, Wkb, bk, Ls, d_out,
            512, 512, 512, 512, (long)SS * DD, 0, 0, 0, 0, 0, 0);
    } else {
        // fallback: fused flash attention (r15)
        k_attn<<<512, 512, 0, stream>>>(Vtb, Xb, Xbt, Vtb);
        k_bgemm<2><<<dim3(16, 4, 16), 256, 0, stream>>>(
            Vtb, Wkb, bk, nullptr, d_out,
            512, 512, 512, 512, (long)SS * DD, 0, 0, 0, 0, 0, 0);
        // note: fallback k_attn already divides by row-sums; MODE 2 would
        // divide again — so fallback uses a bias-only path instead:
        // (overwritten below)
    }
}

// Round 18
// 326.823 us; speedup vs baseline: 1.1324x; 1.0523x over previous
//
#include <hip/hip_runtime.h>
#include <hip/hip_bf16.h>

#define SS 2048
#define BB 16
#define DD 512

typedef __attribute__((ext_vector_type(4))) float f32x4;
typedef __attribute__((ext_vector_type(8))) short bf16x8;
typedef __attribute__((ext_vector_type(4))) unsigned short us4;
typedef unsigned short us;

#define MFMA16(a,b,c) __builtin_amdgcn_mfma_f32_16x16x32_bf16((a),(b),(c),0,0,0)
#define BAR() __builtin_amdgcn_s_barrier()
#define WAITV(n) asm volatile("s_waitcnt vmcnt(" #n ")" ::: "memory")
#define WAITL()  asm volatile("s_waitcnt lgkmcnt(0)" ::: "memory")

__device__ __forceinline__ unsigned short f2b(float f) {
    union { float f; unsigned u; } v; v.f = f;
    unsigned r = v.u + 0x7FFFu + ((v.u >> 16) & 1u);
    return (unsigned short)(r >> 16);
}

// 256B-row LDS tile, 4-bit XOR swizzle (16-slot spread)
__device__ __forceinline__ bf16x8 ldfrag8(const us* base, int row, int kelem) {
    int off = (row << 8) + (kelem << 1);
    off ^= (row & 15) << 4;
    return *(const bf16x8*)((const char*)base + off);
}
// 128B-row (gemm tiles)
__device__ __forceinline__ bf16x8 ldfrag(const us* base, int row, int kelem, int rowshift) {
    int off = (row << rowshift) + (kelem << 1);
    off ^= (row & 7) << 4;
    return *(const bf16x8*)((const char*)base + off);
}

__device__ __forceinline__ void gl16(const void* g, void* l) {
    __builtin_amdgcn_global_load_lds(
        (const __attribute__((address_space(1))) unsigned*)g,
        (__attribute__((address_space(3))) unsigned*)l, 16, 0, 0);
}

// ---------------------------------------------------------------------------
// Prep: seq [S][B][D] fp32 -> Xb [B][S][D] bf16 and Xbt [B][D][S] bf16.
// ---------------------------------------------------------------------------
__global__ __launch_bounds__(256) void k_prep_x(const float* __restrict__ seq,
        us* __restrict__ Xb, us* __restrict__ Xbt) {
    __shared__ __align__(16) char L[64 * 128];
    const int tid = threadIdx.x;
    const int d0 = blockIdx.x * 64, s0 = blockIdx.y * 64, b = blockIdx.z;
    {
        int r = tid >> 2, seg = (tid & 3) * 16;
        const float* src = seq + (size_t)(s0 + r) * (BB * DD) + (size_t)b * DD + d0 + seg;
        __align__(16) us vals[16];
        #pragma unroll
        for (int q = 0; q < 4; ++q) {
            f32x4 v = *(const f32x4*)(src + q * 4);
            vals[q*4+0] = f2b(v.x); vals[q*4+1] = f2b(v.y);
            vals[q*4+2] = f2b(v.z); vals[q*4+3] = f2b(v.w);
        }
        us* xo = Xb + ((size_t)b * SS + s0 + r) * DD + d0 + seg;
        *(bf16x8*)xo       = *(bf16x8*)&vals[0];
        *(bf16x8*)(xo + 8) = *(bf16x8*)&vals[8];
        #pragma unroll
        for (int j = 0; j < 16; ++j) {
            int d = seg + j;
            int addr = (d * 128 + r * 2) ^ ((d & 7) << 4);
            *(us*)(L + addr) = vals[j];
        }
    }
    __syncthreads();
    {
        int d = tid >> 2, sseg = (tid & 3) * 16;
        int c = (d & 7) << 4;
        int base = d * 128 + sseg * 2;
        bf16x8 h0 = *(bf16x8*)(L + (base ^ c));
        bf16x8 h1 = *(bf16x8*)(L + ((base + 16) ^ c));
        us* o = Xbt + ((size_t)b * DD + d0 + d) * SS + s0 + sseg;
        *(bf16x8*)o       = h0;
        *(bf16x8*)(o + 8) = h1;
    }
}

// ---------------------------------------------------------------------------
// Gt[p][i] = (1/sqrt(D)) * sum_a Wv[a,i] * Wq[a,p]
// ---------------------------------------------------------------------------
__global__ __launch_bounds__(256) void k_prepG(const float* __restrict__ Wv,
        const float* __restrict__ Wq, us* __restrict__ Gt) {
    __shared__ float Sq[32][64], Sv[32][64];
    const int tid = threadIdx.x;
    const int p0 = blockIdx.x * 64, i0 = blockIdx.y * 64;
    const int tp = tid & 15, ti = tid >> 4;
    float acc[4][4] = {};
    for (int a0 = 0; a0 < DD; a0 += 32) {
        #pragma unroll
        for (int j = 0; j < 2; ++j) {
            int slot = tid + j * 256;
            int row = slot >> 4, c4 = (slot & 15) * 4;
            *(f32x4*)&Sq[row][c4] = *(const f32x4*)(Wq + (size_t)(a0 + row) * DD + p0 + c4);
            *(f32x4*)&Sv[row][c4] = *(const f32x4*)(Wv + (size_t)(a0 + row) * DD + i0 + c4);
        }
        __syncthreads();
        for (int a = 0; a < 32; ++a) {
            f32x4 q = *(f32x4*)&Sq[a][tp * 4];
            f32x4 v = *(f32x4*)&Sv[a][ti * 4];
            #pragma unroll
            for (int x = 0; x < 4; ++x)
                #pragma unroll
                for (int y = 0; y < 4; ++y)
                    acc[x][y] += q[x] * v[y];
        }
        __syncthreads();
    }
    const float sc = 0.044194173824159216f;
    #pragma unroll
    for (int x = 0; x < 4; ++x)
        #pragma unroll
        for (int y = 0; y < 4; ++y)
            Gt[(size_t)(p0 + tp * 4 + x) * DD + i0 + ti * 4 + y] = f2b(acc[x][y] * sc);
}

// u[p] = (1/sqrt(D)) * sum_a bv[a] * Wq[a,p]
__global__ __launch_bounds__(512) void k_prepU(const float* __restrict__ Wq,
        const float* __restrict__ bv, float* __restrict__ u) {
    int p = threadIdx.x;
    float s = 0.f;
    for (int a0 = 0; a0 < DD; a0 += 8) {
        #pragma unroll
        for (int j = 0; j < 8; ++j)
            s += bv[a0 + j] * Wq[(size_t)(a0 + j) * DD + p];
    }
    u[p] = s * 0.044194173824159216f;
}

__global__ void k_prepW(const float* __restrict__ Wk, us* __restrict__ Wkb) {
    int i = (blockIdx.x * 256 + threadIdx.x) * 4;
    f32x4 v = *(const f32x4*)(Wk + i);
    us4 o; o.x = f2b(v.x); o.y = f2b(v.y); o.z = f2b(v.z); o.w = f2b(v.w);
    *(us4*)(Wkb + i) = o;
}

// ---------------------------------------------------------------------------
// Generalized batched bf16 GEMM, 128x128 tile, BK=64, dbuf+counted vmcnt.
//   C[row,n] = sum_k A[za][s0+row][k] * B[zb][n0+n][k]
//   MODE 0: P = exp(acc) -> bf16 out (no row-sum work).
//   MODE 1: bf16 out; ALSO row-sums of A (P) via ones-MFMA -> Ls (plain store).
//   MODE 2: fp32 out at [(row*BB+zo)*DD+col] = acc/Ls[row] + bias[col].
//   MODE 3: bf16 out + bias.
//   MODE 4: fp32 out + bias (no Ls divide)  [fallback path].
// ---------------------------------------------------------------------------
template<int MODE>
__global__ __launch_bounds__(256, 2) void k_bgemm(
        const us* __restrict__ A, const us* __restrict__ Bm,
        const float* __restrict__ bias, float* __restrict__ Ls,
        void* __restrict__ outp,
        int K, int lda, int ldb, int ldc,
        long aStr, long bStr, long oStr,
        int aB, int bB, int oB, int lsB) {
    __shared__ __align__(16) us As[2][128 * 64];
    __shared__ __align__(16) us Bs[2][128 * 64];
    const int tid = threadIdx.x;
    const int lane = tid & 63;
    const int w = tid >> 6;
    const int wr = w >> 1, wc = w & 1;
    const int l15 = lane & 15, lg = lane >> 4;
    const int s0 = blockIdx.x * 128;
    const int n0 = blockIdx.y * 128;
    const int za = aB + blockIdx.z, zb = bB + blockIdx.z;
    const int zo = oB + blockIdx.z, zl = lsB + blockIdx.z;
    const char* abase = (const char*)(A + (size_t)za * aStr + (size_t)s0 * lda);
    const char* bbase = (const char*)(Bm + (size_t)zb * bStr + (size_t)n0 * ldb);
    const size_t arow = (size_t)lda * 2, brow = (size_t)ldb * 2;

    const short one_bf = (short)0x3F80;
    const bf16x8 ones = {one_bf, one_bf, one_bf, one_bf,
                         one_bf, one_bf, one_bf, one_bf};

    f32x4 acc[4][4];
    #pragma unroll
    for (int m = 0; m < 4; ++m)
        #pragma unroll
        for (int n = 0; n < 4; ++n) acc[m][n] = (f32x4)(0.0f);
    f32x4 lsum[4];
    #pragma unroll
    for (int m = 0; m < 4; ++m) lsum[m] = (f32x4)(0.0f);

    auto stage = [&](int db, int p) {
        #pragma unroll
        for (int j = 0; j < 4; ++j) {
            int x = (tid + j * 256) * 16;
            int gx = x ^ (((x >> 7) & 7) << 4);
            int row = gx >> 7, col = gx & 127;
            gl16(abase + (size_t)row * arow + p * 128 + col, (char*)As[db] + x);
            gl16(bbase + (size_t)row * brow + p * 128 + col, (char*)Bs[db] + x);
        }
    };

    const int nPh = K >> 6;
    stage(0, 0);
    for (int p = 0; p < nPh; ++p) {
        if (p < nPh - 1) { stage((p + 1) & 1, p + 1); WAITV(8); }
        else             { WAITV(0); }
        BAR();
        const us* Ac = As[p & 1]; const us* Bc = Bs[p & 1];
        __builtin_amdgcn_s_setprio(1);
        #pragma unroll
        for (int kk = 0; kk < 2; ++kk) {
            bf16x8 af[4], bfr[4];
            #pragma unroll
            for (int m = 0; m < 4; ++m) af[m]  = ldfrag(Ac, 64 * wr + 16 * m + l15, kk * 32 + 8 * lg, 7);
            #pragma unroll
            for (int n = 0; n < 4; ++n) bfr[n] = ldfrag(Bc, 64 * wc + 16 * n + l15, kk * 32 + 8 * lg, 7);
            #pragma unroll
            for (int m = 0; m < 4; ++m)
                #pragma unroll
                for (int n = 0; n < 4; ++n)
                    acc[m][n] = MFMA16(af[m], bfr[n], acc[m][n]);
            if (MODE == 1) {
                #pragma unroll
                for (int m = 0; m < 4; ++m)
                    lsum[m] = MFMA16(af[m], ones, lsum[m]);
            }
        }
        __builtin_amdgcn_s_setprio(0);
        BAR();
    }

    if (MODE == 0) {
        us* o = (us*)outp + (size_t)zo * oStr;
        #pragma unroll
        for (int m = 0; m < 4; ++m)
            #pragma unroll
            for (int n = 0; n < 4; ++n) {
                int col = n0 + 64 * wc + 16 * n + l15;
                #pragma unroll
                for (int r = 0; r < 4; ++r) {
                    int row = s0 + 64 * wr + 16 * m + 4 * lg + r;
                    o[(size_t)row * ldc + col] = f2b(__expf(acc[m][n][r]));
                }
            }
    } else if (MODE == 2 || MODE == 4) {
        float* o = (float*)outp;
        #pragma unroll
        for (int m = 0; m < 4; ++m)
            #pragma unroll
            for (int n = 0; n < 4; ++n) {
                int col = n0 + 64 * wc + 16 * n + l15;
                float bia = bias[col];
                #pragma unroll
                for (int r = 0; r < 4; ++r) {
                    int row = s0 + 64 * wr + 16 * m + 4 * lg + r;
                    float v = acc[m][n][r];
                    if (MODE == 2) v /= Ls[(size_t)zl * SS + row];
                    o[((size_t)row * BB + zo) * DD + col] = v + bia;
                }
            }
    } else {
        us* o = (us*)outp + (size_t)zo * oStr;
        #pragma unroll
        for (int m = 0; m < 4; ++m)
            #pragma unroll
            for (int n = 0; n < 4; ++n) {
                int col = n0 + 64 * wc + 16 * n + l15;
                float bia = (MODE == 3) ? bias[col] : 0.0f;
                #pragma unroll
                for (int r = 0; r < 4; ++r) {
                    int row = s0 + 64 * wr + 16 * m + 4 * lg + r;
                    o[(size_t)row * ldc + col] = f2b(acc[m][n][r] + bia);
                }
            }
        if (MODE == 1) {
            #pragma unroll
            for (int m = 0; m < 4; ++m)
                #pragma unroll
                for (int r = 0; r < 4; ++r)
                    if (l15 == 0)
                        Ls[(size_t)zl * SS + s0 + 64 * wr + 16 * m + 4 * lg + r] = lsum[m][r];
        }
    }
}

// ---------------------------------------------------------------------------
// FALLBACK flash attention (r15 v19, 249us) — used only if ws too small.
// Output O' is ALREADY divided by row-sums; pair with MODE 4.
// ---------------------------------------------------------------------------
__global__ __launch_bounds__(512, 2) void k_attn(
        const us* __restrict__ Vtb, const us* __restrict__ Xb,
        const us* __restrict__ Xbt, us* __restrict__ Ob) {
    __shared__ __align__(16) us BUFS[4][16384];
    __shared__ __align__(16) us Pb[64 * 128];
    __shared__ float red[2][64];

    const int tid = threadIdx.x;
    const int lane = tid & 63;
    const int w = tid >> 6;
    const int rg = w & 3;
    const int cg = w >> 2;
    const int l15 = lane & 15, lg = lane >> 4;

    const int wg = blockIdx.x;
    const int b  = ((wg >> 8) << 3) | (wg & 7);
    const int s0 = ((wg >> 3) & 31) * 64;

    const char* vbase  = (const char*)(Vtb + ((size_t)b * SS + s0) * DD);
    const char* xabase = (const char*)(Xb  + (size_t)b * SS * DD);
    const char* xtbase = (const char*)(Xbt + (size_t)b * DD * SS);

    auto issue = [&](int cflat, us* dst0) {
        int c = cflat & 127;
        int i = c & 7, t0 = (c >> 3) << 7;
        char* dst = (char*)dst0;
        if (i < 4) {
            #pragma unroll
            for (int j = 0; j < 4; ++j) {
                int x = tid * 16 + j * 8192;
                int gx = x ^ (((x >> 8) & 15) << 4);
                int row = gx >> 8, col = gx & 255;
                gl16(xabase + (size_t)(t0 + row) * 1024 + i * 256 + col, dst + x);
            }
        } else {
            #pragma unroll
            for (int j = 0; j < 4; ++j) {
                int x = tid * 16 + j * 8192;
                int gx = x ^ (((x >> 8) & 15) << 4);
                int row = gx >> 8, col = gx & 255;
                gl16(xtbase + (size_t)((i - 4) * 128 + row) * (SS * 2)
                            + (size_t)t0 * 2 + col, dst + x);
            }
        }
    };

    #pragma unroll
    for (int p = 0; p < 4; ++p) {
        #pragma unroll
        for (int j = 0; j < 2; ++j) {
            int x = tid * 16 + j * 8192;
            int gx = x ^ (((x >> 8) & 15) << 4);
            int row = gx >> 8, col = gx & 255;
            gl16(vbase + (size_t)row * 1024 + p * 256 + col,
                 (char*)BUFS[0] + p * 16384 + x);
        }
    }
    WAITV(0); BAR();
    bf16x8 af[16];
    #pragma unroll
    for (int p = 0; p < 4; ++p)
        #pragma unroll
        for (int kk = 0; kk < 4; ++kk)
            af[4 * p + kk] = ldfrag8((const us*)BUFS[0] + p * 8192,
                                     16 * rg + l15, 32 * kk + 8 * lg);
    WAITL(); BAR();

    issue(0, BUFS[0]);
    issue(1, BUFS[1]);
    issue(2, BUFS[2]);

    f32x4 accv[4][4];
    #pragma unroll
    for (int ph = 0; ph < 4; ++ph)
        #pragma unroll
        for (int nt = 0; nt < 4; ++nt) accv[ph][nt] = (f32x4)(0.0f);
    float lsum[4] = {0.f, 0.f, 0.f, 0.f};
    const int idx = 16 * rg + 4 * lg;

    for (int step = 0; step < 16; ++step) {
        const int cbase = step * 8;
        f32x4 sacc[4];
        #pragma unroll
        for (int nt = 0; nt < 4; ++nt) sacc[nt] = (f32x4)(0.0f);

        #pragma unroll
        for (int p = 0; p < 4; ++p) {
            const int c = cbase + p;
            WAITV(8); BAR();
            const us* sl = BUFS[c & 3];
            __builtin_amdgcn_s_setprio(1);
            #pragma unroll
            for (int kk = 0; kk < 4; ++kk)
                #pragma unroll
                for (int nt = 0; nt < 4; ++nt) {
                    bf16x8 bq = ldfrag8(sl, 64 * cg + 16 * nt + l15, 32 * kk + 8 * lg);
                    sacc[nt] = MFMA16(af[4 * p + kk], bq, sacc[nt]);
                }
            __builtin_amdgcn_s_setprio(0);
            issue(c + 3, BUFS[(c + 3) & 3]);
        }

        #pragma unroll
        for (int nt = 0; nt < 4; ++nt)
            #pragma unroll
            for (int ri = 0; ri < 4; ++ri)
                sacc[nt][ri] = __expf(sacc[nt][ri]);
        #pragma unroll
        for (int nt = 0; nt < 4; ++nt)
            #pragma unroll
            for (int ri = 0; ri < 4; ++ri) {
                int row = idx + ri;
                int col = 64 * cg + 16 * nt + l15;
                int off = ((row << 8) + (col << 1)) ^ ((row & 15) << 4);
                *(us*)((char*)Pb + off) = f2b(sacc[nt][ri]);
            }
        #pragma unroll
        for (int ri = 0; ri < 4; ++ri) {
            float s = sacc[0][ri] + sacc[1][ri] + sacc[2][ri] + sacc[3][ri];
            s += __shfl_xor(s, 1); s += __shfl_xor(s, 2);
            s += __shfl_xor(s, 4); s += __shfl_xor(s, 8);
            lsum[ri] += s;
        }
        WAITL(); BAR();
        bf16x8 pa[4];
        #pragma unroll
        for (int kk = 0; kk < 4; ++kk)
            pa[kk] = ldfrag8(Pb, 16 * rg + l15, 32 * kk + 8 * lg);

        #pragma unroll
        for (int p = 0; p < 4; ++p) {
            const int c = cbase + 4 + p;
            WAITV(8); BAR();
            const us* sl = BUFS[c & 3];
            __builtin_amdgcn_s_setprio(1);
            #pragma unroll
            for (int kk = 0; kk < 4; ++kk)
                #pragma unroll
                for (int nt = 0; nt < 4; ++nt) {
                    bf16x8 bx = ldfrag8(sl, 64 * cg + 16 * nt + l15, 32 * kk + 8 * lg);
                    accv[p][nt] = MFMA16(pa[kk], bx, accv[p][nt]);
                }
            __builtin_amdgcn_s_setprio(0);
            issue(c + 3, BUFS[(c + 3) & 3]);
        }
    }

    WAITV(0);
    if (l15 == 0) {
        #pragma unroll
        for (int ri = 0; ri < 4; ++ri)
            red[cg][idx + ri] = lsum[ri];
    }
    WAITL(); BAR();
    float tot[4];
    #pragma unroll
    for (int ri = 0; ri < 4; ++ri)
        tot[ri] = red[0][idx + ri] + red[1][idx + ri];
    us* orow = Ob + ((size_t)b * SS + s0) * DD;
    #pragma unroll
    for (int ph = 0; ph < 4; ++ph)
        #pragma unroll
        for (int nt = 0; nt < 4; ++nt)
            #pragma unroll
            for (int ri = 0; ri < 4; ++ri) {
                int row = idx + ri;
                int e = 128 * ph + 64 * cg + 16 * nt + l15;
                orow[(size_t)row * DD + e] = f2b(accv[ph][nt][ri] / tot[ri]);
            }
}

extern "C" void kernel_launch(void* const* d_in, const int* in_sizes, int n_in,
                              void* d_out, int out_size, void* d_ws, size_t ws_size,
                              hipStream_t stream) {
    const float* seq = (const float*)d_in[0];
    const float* Wv  = (const float*)d_in[1];
    const float* bv  = (const float*)d_in[2];
    const float* Wq  = (const float*)d_in[3];
    // d_in[4] = bq: softmax-row-constant -> unused
    const float* Wk  = (const float*)d_in[5];
    const float* bk  = (const float*)d_in[6];

    char* ws = (char*)d_ws;
    us*    Xb  = (us*)ws;                                  // [B][S][D] bf16, 32MB
    us*    Xbt = (us*)(ws + (size_t)33554432);             // [B][D][S] bf16, 32MB
    us*    Vtb = (us*)(ws + (size_t)67108864);             // [B][S][D] bf16, 32MB
    us*    Gt  = (us*)(ws + (size_t)100663296);            // [D][D] bf16
    us*    Wkb = (us*)(ws + (size_t)101187584);            // [D][D] bf16
    float* u   = (float*)(ws + (size_t)101711872);         // [D] fp32
    float* Ls  = (float*)(ws + (size_t)101713920);         // [B][S] fp32, 128KB
    const size_t POFF = 101844992ull;
    us*    P   = (us*)(ws + POFF);                         // [gb][S][S] bf16

    long gb = 0;
    if (ws_size > POFF) {
        size_t cap = ws_size - POFF;
        for (long g = 8; g >= 1; g >>= 1)              // cap at 8: keep P L3-resident
            if ((size_t)g * SS * SS * 2 <= cap) { gb = g; break; }
    }

    k_prep_x<<<dim3(8, 32, 16), 256, 0, stream>>>(seq, Xb, Xbt);
    k_prepG<<<dim3(8, 8), 256, 0, stream>>>(Wv, Wq, Gt);
    k_prepU<<<1, 512, 0, stream>>>(Wq, bv, u);
    k_prepW<<<256, 256, 0, stream>>>(Wk, Wkb);

    // Vt = X*G + u  (bf16 out, bias)
    k_bgemm<3><<<dim3(16, 4, 16), 256, 0, stream>>>(
        Xb, Gt, u, nullptr, (void*)Vtb,
        512, 512, 512, 512, (long)SS * DD, 0, (long)SS * DD, 0, 0, 0, 0);

    if (gb >= 1) {
        for (int g = 0; g < 16; g += (int)gb) {
            // P = exp(Vt * X^T)  (row-sums deferred to MODE 1)
            k_bgemm<0><<<dim3(16, 16, (int)gb), 256, 0, stream>>>(
                Vtb, Xb, nullptr, nullptr, (void*)P,
                512, 512, 512, 2048, (long)SS * DD, (long)SS * DD, (long)SS * SS,
                g, g, 0, 0);
            // O' = P * X (via Xbt), overwrite Vtb; row-sums of P -> Ls
            k_bgemm<1><<<dim3(16, 4, (int)gb), 256, 0, stream>>>(
                P, Xbt, nullptr, Ls, (void*)Vtb,
                2048, 2048, 2048, 512, (long)SS * SS, (long)DD * SS, (long)SS * DD,
                0, g, g, g);
        }
        // out = (O' / L) * Wk^T + bk   (fp32, [S][B][D])
        k_bgemm<2><<<dim3(16, 4, 16), 256, 0, stream>>>(
            Vtb, Wkb, bk, Ls, d_out,
            512, 512, 512, 512, (long)SS * DD, 0, 0, 0, 0, 0, 0);
    } else {
        // fallback: fused flash attention (already normalized) + plain GEMM
        k_attn<<<512, 512, 0, stream>>>(Vtb, Xb, Xbt, Vtb);
        k_bgemm<4><<<dim3(16, 4, 16), 256, 0, stream>>>(
            Vtb, Wkb, bk, nullptr, d_out,
            512, 512, 512, 512, (long)SS * DD, 0, 0, 0, 0, 0, 0);
    }
}

// Round 19
// 326.031 us; speedup vs baseline: 1.1351x; 1.0024x over previous
//
#include <hip/hip_runtime.h>
#include <hip/hip_bf16.h>

#define SS 2048
#define BB 16
#define DD 512

typedef __attribute__((ext_vector_type(4))) float f32x4;
typedef __attribute__((ext_vector_type(8))) short bf16x8;
typedef __attribute__((ext_vector_type(4))) unsigned short us4;
typedef unsigned short us;

#define MFMA16(a,b,c) __builtin_amdgcn_mfma_f32_16x16x32_bf16((a),(b),(c),0,0,0)
#define BAR() __builtin_amdgcn_s_barrier()
#define WAITV(n) asm volatile("s_waitcnt vmcnt(" #n ")" ::: "memory")
#define WAITL()  asm volatile("s_waitcnt lgkmcnt(0)" ::: "memory")

__device__ __forceinline__ unsigned short f2b(float f) {
    union { float f; unsigned u; } v; v.f = f;
    unsigned r = v.u + 0x7FFFu + ((v.u >> 16) & 1u);
    return (unsigned short)(r >> 16);
}

// 256B-row LDS tile, 4-bit XOR swizzle (16-slot spread)
__device__ __forceinline__ bf16x8 ldfrag8(const us* base, int row, int kelem) {
    int off = (row << 8) + (kelem << 1);
    off ^= (row & 15) << 4;
    return *(const bf16x8*)((const char*)base + off);
}
// 128B-row (gemm tiles)
__device__ __forceinline__ bf16x8 ldfrag(const us* base, int row, int kelem, int rowshift) {
    int off = (row << rowshift) + (kelem << 1);
    off ^= (row & 7) << 4;
    return *(const bf16x8*)((const char*)base + off);
}

__device__ __forceinline__ void gl16(const void* g, void* l) {
    __builtin_amdgcn_global_load_lds(
        (const __attribute__((address_space(1))) unsigned*)g,
        (__attribute__((address_space(3))) unsigned*)l, 16, 0, 0);
}

// ---------------------------------------------------------------------------
// Prep: seq [S][B][D] fp32 -> Xb [B][S][D] bf16 and Xbt [B][D][S] bf16.
// ---------------------------------------------------------------------------
__global__ __launch_bounds__(256) void k_prep_x(const float* __restrict__ seq,
        us* __restrict__ Xb, us* __restrict__ Xbt) {
    __shared__ __align__(16) char L[64 * 128];
    const int tid = threadIdx.x;
    const int d0 = blockIdx.x * 64, s0 = blockIdx.y * 64, b = blockIdx.z;
    {
        int r = tid >> 2, seg = (tid & 3) * 16;
        const float* src = seq + (size_t)(s0 + r) * (BB * DD) + (size_t)b * DD + d0 + seg;
        __align__(16) us vals[16];
        #pragma unroll
        for (int q = 0; q < 4; ++q) {
            f32x4 v = *(const f32x4*)(src + q * 4);
            vals[q*4+0] = f2b(v.x); vals[q*4+1] = f2b(v.y);
            vals[q*4+2] = f2b(v.z); vals[q*4+3] = f2b(v.w);
        }
        us* xo = Xb + ((size_t)b * SS + s0 + r) * DD + d0 + seg;
        *(bf16x8*)xo       = *(bf16x8*)&vals[0];
        *(bf16x8*)(xo + 8) = *(bf16x8*)&vals[8];
        #pragma unroll
        for (int j = 0; j < 16; ++j) {
            int d = seg + j;
            int addr = (d * 128 + r * 2) ^ ((d & 7) << 4);
            *(us*)(L + addr) = vals[j];
        }
    }
    __syncthreads();
    {
        int d = tid >> 2, sseg = (tid & 3) * 16;
        int c = (d & 7) << 4;
        int base = d * 128 + sseg * 2;
        bf16x8 h0 = *(bf16x8*)(L + (base ^ c));
        bf16x8 h1 = *(bf16x8*)(L + ((base + 16) ^ c));
        us* o = Xbt + ((size_t)b * DD + d0 + d) * SS + s0 + sseg;
        *(bf16x8*)o       = h0;
        *(bf16x8*)(o + 8) = h1;
    }
}

// ---------------------------------------------------------------------------
// Gt[p][i] = (1/sqrt(D)) * sum_a Wv[a,i] * Wq[a,p]
// ---------------------------------------------------------------------------
__global__ __launch_bounds__(256) void k_prepG(const float* __restrict__ Wv,
        const float* __restrict__ Wq, us* __restrict__ Gt) {
    __shared__ float Sq[32][64], Sv[32][64];
    const int tid = threadIdx.x;
    const int p0 = blockIdx.x * 64, i0 = blockIdx.y * 64;
    const int tp = tid & 15, ti = tid >> 4;
    float acc[4][4] = {};
    for (int a0 = 0; a0 < DD; a0 += 32) {
        #pragma unroll
        for (int j = 0; j < 2; ++j) {
            int slot = tid + j * 256;
            int row = slot >> 4, c4 = (slot & 15) * 4;
            *(f32x4*)&Sq[row][c4] = *(const f32x4*)(Wq + (size_t)(a0 + row) * DD + p0 + c4);
            *(f32x4*)&Sv[row][c4] = *(const f32x4*)(Wv + (size_t)(a0 + row) * DD + i0 + c4);
        }
        __syncthreads();
        for (int a = 0; a < 32; ++a) {
            f32x4 q = *(f32x4*)&Sq[a][tp * 4];
            f32x4 v = *(f32x4*)&Sv[a][ti * 4];
            #pragma unroll
            for (int x = 0; x < 4; ++x)
                #pragma unroll
                for (int y = 0; y < 4; ++y)
                    acc[x][y] += q[x] * v[y];
        }
        __syncthreads();
    }
    const float sc = 0.044194173824159216f;
    #pragma unroll
    for (int x = 0; x < 4; ++x)
        #pragma unroll
        for (int y = 0; y < 4; ++y)
            Gt[(size_t)(p0 + tp * 4 + x) * DD + i0 + ti * 4 + y] = f2b(acc[x][y] * sc);
}

// u[p] = (1/sqrt(D)) * sum_a bv[a] * Wq[a,p]
__global__ __launch_bounds__(512) void k_prepU(const float* __restrict__ Wq,
        const float* __restrict__ bv, float* __restrict__ u) {
    int p = threadIdx.x;
    float s = 0.f;
    for (int a0 = 0; a0 < DD; a0 += 8) {
        #pragma unroll
        for (int j = 0; j < 8; ++j)
            s += bv[a0 + j] * Wq[(size_t)(a0 + j) * DD + p];
    }
    u[p] = s * 0.044194173824159216f;
}

__global__ void k_prepW(const float* __restrict__ Wk, us* __restrict__ Wkb) {
    int i = (blockIdx.x * 256 + threadIdx.x) * 4;
    f32x4 v = *(const f32x4*)(Wk + i);
    us4 o; o.x = f2b(v.x); o.y = f2b(v.y); o.z = f2b(v.z); o.w = f2b(v.w);
    *(us4*)(Wkb + i) = o;
}

// ---------------------------------------------------------------------------
// Generalized batched bf16 GEMM, 128x128 tile, BK=64, dbuf+counted vmcnt.
// 1-D flat grid with XCD-local decode: z = flat & ((1<<zBits)-1)  -> each
// XCD's co-resident blocks share one batch (L2-resident operand panels).
//   idx = flat >> zBits; s0 = (idx & sMask)*128; n0 = (idx >> sBits)*128.
//   MODE 0: P = exp(acc) -> bf16 out.
//   MODE 1: bf16 out; row-sums of A via ones-MFMA -> Ls.
//   MODE 2: fp32 out at [(row*BB+zo)*DD+col] = acc/Ls[row] + bias[col].
//   MODE 3: bf16 out + bias.
//   MODE 4: fp32 out + bias (no divide) [fallback].
// ---------------------------------------------------------------------------
template<int MODE>
__global__ __launch_bounds__(256, 2) void k_bgemm(
        const us* __restrict__ A, const us* __restrict__ Bm,
        const float* __restrict__ bias, float* __restrict__ Ls,
        void* __restrict__ outp,
        int K, int lda, int ldb, int ldc,
        long aStr, long bStr, long oStr,
        int aB, int bB, int oB, int lsB,
        int zBits, int sBits) {
    __shared__ __align__(16) us As[2][128 * 64];
    __shared__ __align__(16) us Bs[2][128 * 64];
    const int tid = threadIdx.x;
    const int lane = tid & 63;
    const int w = tid >> 6;
    const int wr = w >> 1, wc = w & 1;
    const int l15 = lane & 15, lg = lane >> 4;

    const int flat = blockIdx.x;
    const int z = flat & ((1 << zBits) - 1);
    const int idx = flat >> zBits;
    const int s0 = (idx & ((1 << sBits) - 1)) << 7;
    const int n0 = (idx >> sBits) << 7;

    const int za = aB + z, zb = bB + z;
    const int zo = oB + z, zl = lsB + z;
    const char* abase = (const char*)(A + (size_t)za * aStr + (size_t)s0 * lda);
    const char* bbase = (const char*)(Bm + (size_t)zb * bStr + (size_t)n0 * ldb);
    const size_t arow = (size_t)lda * 2, brow = (size_t)ldb * 2;

    const short one_bf = (short)0x3F80;
    const bf16x8 ones = {one_bf, one_bf, one_bf, one_bf,
                         one_bf, one_bf, one_bf, one_bf};

    f32x4 acc[4][4];
    #pragma unroll
    for (int m = 0; m < 4; ++m)
        #pragma unroll
        for (int n = 0; n < 4; ++n) acc[m][n] = (f32x4)(0.0f);
    f32x4 lsum[4];
    #pragma unroll
    for (int m = 0; m < 4; ++m) lsum[m] = (f32x4)(0.0f);

    auto stage = [&](int db, int p) {
        #pragma unroll
        for (int j = 0; j < 4; ++j) {
            int x = (tid + j * 256) * 16;
            int gx = x ^ (((x >> 7) & 7) << 4);
            int row = gx >> 7, col = gx & 127;
            gl16(abase + (size_t)row * arow + p * 128 + col, (char*)As[db] + x);
            gl16(bbase + (size_t)row * brow + p * 128 + col, (char*)Bs[db] + x);
        }
    };

    const int nPh = K >> 6;
    stage(0, 0);
    for (int p = 0; p < nPh; ++p) {
        if (p < nPh - 1) { stage((p + 1) & 1, p + 1); WAITV(8); }
        else             { WAITV(0); }
        BAR();
        const us* Ac = As[p & 1]; const us* Bc = Bs[p & 1];
        __builtin_amdgcn_s_setprio(1);
        #pragma unroll
        for (int kk = 0; kk < 2; ++kk) {
            bf16x8 af[4], bfr[4];
            #pragma unroll
            for (int m = 0; m < 4; ++m) af[m]  = ldfrag(Ac, 64 * wr + 16 * m + l15, kk * 32 + 8 * lg, 7);
            #pragma unroll
            for (int n = 0; n < 4; ++n) bfr[n] = ldfrag(Bc, 64 * wc + 16 * n + l15, kk * 32 + 8 * lg, 7);
            #pragma unroll
            for (int m = 0; m < 4; ++m)
                #pragma unroll
                for (int n = 0; n < 4; ++n)
                    acc[m][n] = MFMA16(af[m], bfr[n], acc[m][n]);
            if (MODE == 1) {
                #pragma unroll
                for (int m = 0; m < 4; ++m)
                    lsum[m] = MFMA16(af[m], ones, lsum[m]);
            }
        }
        __builtin_amdgcn_s_setprio(0);
        BAR();
    }

    if (MODE == 0) {
        us* o = (us*)outp + (size_t)zo * oStr;
        #pragma unroll
        for (int m = 0; m < 4; ++m)
            #pragma unroll
            for (int n = 0; n < 4; ++n) {
                int col = n0 + 64 * wc + 16 * n + l15;
                #pragma unroll
                for (int r = 0; r < 4; ++r) {
                    int row = s0 + 64 * wr + 16 * m + 4 * lg + r;
                    o[(size_t)row * ldc + col] = f2b(__expf(acc[m][n][r]));
                }
            }
    } else if (MODE == 2 || MODE == 4) {
        float* o = (float*)outp;
        #pragma unroll
        for (int m = 0; m < 4; ++m)
            #pragma unroll
            for (int n = 0; n < 4; ++n) {
                int col = n0 + 64 * wc + 16 * n + l15;
                float bia = bias[col];
                #pragma unroll
                for (int r = 0; r < 4; ++r) {
                    int row = s0 + 64 * wr + 16 * m + 4 * lg + r;
                    float v = acc[m][n][r];
                    if (MODE == 2) v /= Ls[(size_t)zl * SS + row];
                    o[((size_t)row * BB + zo) * DD + col] = v + bia;
                }
            }
    } else {
        us* o = (us*)outp + (size_t)zo * oStr;
        #pragma unroll
        for (int m = 0; m < 4; ++m)
            #pragma unroll
            for (int n = 0; n < 4; ++n) {
                int col = n0 + 64 * wc + 16 * n + l15;
                float bia = (MODE == 3) ? bias[col] : 0.0f;
                #pragma unroll
                for (int r = 0; r < 4; ++r) {
                    int row = s0 + 64 * wr + 16 * m + 4 * lg + r;
                    o[(size_t)row * ldc + col] = f2b(acc[m][n][r] + bia);
                }
            }
        if (MODE == 1) {
            #pragma unroll
            for (int m = 0; m < 4; ++m)
                #pragma unroll
                for (int r = 0; r < 4; ++r)
                    if (l15 == 0)
                        Ls[(size_t)zl * SS + s0 + 64 * wr + 16 * m + 4 * lg + r] = lsum[m][r];
        }
    }
}

// ---------------------------------------------------------------------------
// FALLBACK flash attention (r15, 249us) — used only if ws too small.
// Output O' is ALREADY divided by row-sums; pair with MODE 4.
// ---------------------------------------------------------------------------
__global__ __launch_bounds__(512, 2) void k_attn(
        const us* __restrict__ Vtb, const us* __restrict__ Xb,
        const us* __restrict__ Xbt, us* __restrict__ Ob) {
    __shared__ __align__(16) us BUFS[4][16384];
    __shared__ __align__(16) us Pb[64 * 128];
    __shared__ float red[2][64];

    const int tid = threadIdx.x;
    const int lane = tid & 63;
    const int w = tid >> 6;
    const int rg = w & 3;
    const int cg = w >> 2;
    const int l15 = lane & 15, lg = lane >> 4;

    const int wg = blockIdx.x;
    const int b  = ((wg >> 8) << 3) | (wg & 7);
    const int s0 = ((wg >> 3) & 31) * 64;

    const char* vbase  = (const char*)(Vtb + ((size_t)b * SS + s0) * DD);
    const char* xabase = (const char*)(Xb  + (size_t)b * SS * DD);
    const char* xtbase = (const char*)(Xbt + (size_t)b * DD * SS);

    auto issue = [&](int cflat, us* dst0) {
        int c = cflat & 127;
        int i = c & 7, t0 = (c >> 3) << 7;
        char* dst = (char*)dst0;
        if (i < 4) {
            #pragma unroll
            for (int j = 0; j < 4; ++j) {
                int x = tid * 16 + j * 8192;
                int gx = x ^ (((x >> 8) & 15) << 4);
                int row = gx >> 8, col = gx & 255;
                gl16(xabase + (size_t)(t0 + row) * 1024 + i * 256 + col, dst + x);
            }
        } else {
            #pragma unroll
            for (int j = 0; j < 4; ++j) {
                int x = tid * 16 + j * 8192;
                int gx = x ^ (((x >> 8) & 15) << 4);
                int row = gx >> 8, col = gx & 255;
                gl16(xtbase + (size_t)((i - 4) * 128 + row) * (SS * 2)
                            + (size_t)t0 * 2 + col, dst + x);
            }
        }
    };

    #pragma unroll
    for (int p = 0; p < 4; ++p) {
        #pragma unroll
        for (int j = 0; j < 2; ++j) {
            int x = tid * 16 + j * 8192;
            int gx = x ^ (((x >> 8) & 15) << 4);
            int row = gx >> 8, col = gx & 255;
            gl16(vbase + (size_t)row * 1024 + p * 256 + col,
                 (char*)BUFS[0] + p * 16384 + x);
        }
    }
    WAITV(0); BAR();
    bf16x8 af[16];
    #pragma unroll
    for (int p = 0; p < 4; ++p)
        #pragma unroll
        for (int kk = 0; kk < 4; ++kk)
            af[4 * p + kk] = ldfrag8((const us*)BUFS[0] + p * 8192,
                                     16 * rg + l15, 32 * kk + 8 * lg);
    WAITL(); BAR();

    issue(0, BUFS[0]);
    issue(1, BUFS[1]);
    issue(2, BUFS[2]);

    f32x4 accv[4][4];
    #pragma unroll
    for (int ph = 0; ph < 4; ++ph)
        #pragma unroll
        for (int nt = 0; nt < 4; ++nt) accv[ph][nt] = (f32x4)(0.0f);
    float lsum[4] = {0.f, 0.f, 0.f, 0.f};
    const int idx = 16 * rg + 4 * lg;

    for (int step = 0; step < 16; ++step) {
        const int cbase = step * 8;
        f32x4 sacc[4];
        #pragma unroll
        for (int nt = 0; nt < 4; ++nt) sacc[nt] = (f32x4)(0.0f);

        #pragma unroll
        for (int p = 0; p < 4; ++p) {
            const int c = cbase + p;
            WAITV(8); BAR();
            const us* sl = BUFS[c & 3];
            __builtin_amdgcn_s_setprio(1);
            #pragma unroll
            for (int kk = 0; kk < 4; ++kk)
                #pragma unroll
                for (int nt = 0; nt < 4; ++nt) {
                    bf16x8 bq = ldfrag8(sl, 64 * cg + 16 * nt + l15, 32 * kk + 8 * lg);
                    sacc[nt] = MFMA16(af[4 * p + kk], bq, sacc[nt]);
                }
            __builtin_amdgcn_s_setprio(0);
            issue(c + 3, BUFS[(c + 3) & 3]);
        }

        #pragma unroll
        for (int nt = 0; nt < 4; ++nt)
            #pragma unroll
            for (int ri = 0; ri < 4; ++ri)
                sacc[nt][ri] = __expf(sacc[nt][ri]);
        #pragma unroll
        for (int nt = 0; nt < 4; ++nt)
            #pragma unroll
            for (int ri = 0; ri < 4; ++ri) {
                int row = idx + ri;
                int col = 64 * cg + 16 * nt + l15;
                int off = ((row << 8) + (col << 1)) ^ ((row & 15) << 4);
                *(us*)((char*)Pb + off) = f2b(sacc[nt][ri]);
            }
        #pragma unroll
        for (int ri = 0; ri < 4; ++ri) {
            float s = sacc[0][ri] + sacc[1][ri] + sacc[2][ri] + sacc[3][ri];
            s += __shfl_xor(s, 1); s += __shfl_xor(s, 2);
            s += __shfl_xor(s, 4); s += __shfl_xor(s, 8);
            lsum[ri] += s;
        }
        WAITL(); BAR();
        bf16x8 pa[4];
        #pragma unroll
        for (int kk = 0; kk < 4; ++kk)
            pa[kk] = ldfrag8(Pb, 16 * rg + l15, 32 * kk + 8 * lg);

        #pragma unroll
        for (int p = 0; p < 4; ++p) {
            const int c = cbase + 4 + p;
            WAITV(8); BAR();
            const us* sl = BUFS[c & 3];
            __builtin_amdgcn_s_setprio(1);
            #pragma unroll
            for (int kk = 0; kk < 4; ++kk)
                #pragma unroll
                for (int nt = 0; nt < 4; ++nt) {
                    bf16x8 bx = ldfrag8(sl, 64 * cg + 16 * nt + l15, 32 * kk + 8 * lg);
                    accv[p][nt] = MFMA16(pa[kk], bx, accv[p][nt]);
                }
            __builtin_amdgcn_s_setprio(0);
            issue(c + 3, BUFS[(c + 3) & 3]);
        }
    }

    WAITV(0);
    if (l15 == 0) {
        #pragma unroll
        for (int ri = 0; ri < 4; ++ri)
            red[cg][idx + ri] = lsum[ri];
    }
    WAITL(); BAR();
    float tot[4];
    #pragma unroll
    for (int ri = 0; ri < 4; ++ri)
        tot[ri] = red[0][idx + ri] + red[1][idx + ri];
    us* orow = Ob + ((size_t)b * SS + s0) * DD;
    #pragma unroll
    for (int ph = 0; ph < 4; ++ph)
        #pragma unroll
        for (int nt = 0; nt < 4; ++nt)
            #pragma unroll
            for (int ri = 0; ri < 4; ++ri) {
                int row = idx + ri;
                int e = 128 * ph + 64 * cg + 16 * nt + l15;
                orow[(size_t)row * DD + e] = f2b(accv[ph][nt][ri] / tot[ri]);
            }
}

extern "C" void kernel_launch(void* const* d_in, const int* in_sizes, int n_in,
                              void* d_out, int out_size, void* d_ws, size_t ws_size,
                              hipStream_t stream) {
    const float* seq = (const float*)d_in[0];
    const float* Wv  = (const float*)d_in[1];
    const float* bv  = (const float*)d_in[2];
    const float* Wq  = (const float*)d_in[3];
    // d_in[4] = bq: softmax-row-constant -> unused
    const float* Wk  = (const float*)d_in[5];
    const float* bk  = (const float*)d_in[6];

    char* ws = (char*)d_ws;
    us*    Xb  = (us*)ws;                                  // [B][S][D] bf16, 32MB
    us*    Xbt = (us*)(ws + (size_t)33554432);             // [B][D][S] bf16, 32MB
    us*    Vtb = (us*)(ws + (size_t)67108864);             // [B][S][D] bf16, 32MB
    us*    Gt  = (us*)(ws + (size_t)100663296);            // [D][D] bf16
    us*    Wkb = (us*)(ws + (size_t)101187584);            // [D][D] bf16
    float* u   = (float*)(ws + (size_t)101711872);         // [D] fp32
    float* Ls  = (float*)(ws + (size_t)101713920);         // [B][S] fp32, 128KB
    const size_t POFF = 101844992ull;
    us*    P   = (us*)(ws + POFF);                         // [gb][S][S] bf16

    long gb = 0;
    if (ws_size > POFF) {
        size_t cap = ws_size - POFF;
        for (long g = 8; g >= 1; g >>= 1)              // cap at 8: keep P L3-resident
            if ((size_t)g * SS * SS * 2 <= cap) { gb = g; break; }
    }

    k_prep_x<<<dim3(8, 32, 16), 256, 0, stream>>>(seq, Xb, Xbt);
    k_prepG<<<dim3(8, 8), 256, 0, stream>>>(Wv, Wq, Gt);
    k_prepU<<<1, 512, 0, stream>>>(Wq, bv, u);
    k_prepW<<<256, 256, 0, stream>>>(Wk, Wkb);

    // Vt = X*G + u  (bf16 out, bias): z=16 (zBits=4), sTiles=16, nTiles=4
    k_bgemm<3><<<1024, 256, 0, stream>>>(
        Xb, Gt, u, nullptr, (void*)Vtb,
        512, 512, 512, 512, (long)SS * DD, 0, (long)SS * DD, 0, 0, 0, 0,
        4, 4);

    if (gb >= 1) {
        const int zBits = __builtin_ctz((unsigned)gb);
        for (int g = 0; g < 16; g += (int)gb) {
            // P = exp(Vt * X^T): z=gb, sTiles=16, nTiles=16
            k_bgemm<0><<<(int)gb * 256, 256, 0, stream>>>(
                Vtb, Xb, nullptr, nullptr, (void*)P,
                512, 512, 512, 2048, (long)SS * DD, (long)SS * DD, (long)SS * SS,
                g, g, 0, 0, zBits, 4);
            // O' = P * X (via Xbt), overwrite Vtb; row-sums of P -> Ls
            k_bgemm<1><<<(int)gb * 64, 256, 0, stream>>>(
                P, Xbt, nullptr, Ls, (void*)Vtb,
                2048, 2048, 2048, 512, (long)SS * SS, (long)DD * SS, (long)SS * DD,
                0, g, g, g, zBits, 4);
        }
        // out = (O' / L) * Wk^T + bk   (fp32, [S][B][D]): z=16, sTiles=16
        k_bgemm<2><<<1024, 256, 0, stream>>>(
            Vtb, Wkb, bk, Ls, d_out,
            512, 512, 512, 512, (long)SS * DD, 0, 0, 0, 0, 0, 0,
            4, 4);
    } else {
        // fallback: fused flash attention (already normalized) + plain GEMM
        k_attn<<<512, 512, 0, stream>>>(Vtb, Xb, Xbt, Vtb);
        k_bgemm<4><<<1024, 256, 0, stream>>>(
            Vtb, Wkb, bk, nullptr, d_out,
            512, 512, 512, 512, (long)SS * DD, 0, 0, 0, 0, 0, 0,
            4, 4);
    }
}